// Round 17
// baseline (762.639 us; speedup 1.0000x reference)
//
#include <hip/hip_runtime.h>

#define LEAKY 0.2f
#define LN_EPSV 1e-5f
#define NGRAPH 64

typedef __attribute__((ext_vector_type(8))) short short8v;
typedef __attribute__((ext_vector_type(4))) float f32x4;

static __device__ __forceinline__ float leakyf(float x){ return x >= 0.f ? x : LEAKY*x; }

// round-to-nearest-even f32 -> bf16 (as ushort)
static __device__ __forceinline__ unsigned short f2bf(float f){
  unsigned int u = __float_as_uint(f);
  u = (u + 0x7fffu + ((u >> 16) & 1u)) >> 16;
  return (unsigned short)u;
}
static __device__ __forceinline__ float bf2f(unsigned short v){
  return __uint_as_float(((unsigned int)v) << 16);
}

// ---------------- fused front: node encoder + edge_attr mean + count&rank ----------------
// Counting atomic's return value = edge's rank within its dst bucket (stored contiguously),
// so csr_fill needs no atomics. node_encode/ea_mean hide under the atomic wall.
__global__ void front_k(const float* __restrict__ x, const float* __restrict__ w,
                        const float* __restrict__ b, unsigned short* __restrict__ hb, int N,
                        const float* __restrict__ ea, float* __restrict__ emean,
                        const int* __restrict__ dst, int* __restrict__ cnt,
                        int* __restrict__ rank, int E){
  int stride = gridDim.x*blockDim.x;
  int tid0 = blockIdx.x*blockDim.x + threadIdx.x;
  for(int tid = tid0; tid < N*32; tid += stride){
    int n = tid >> 5; int c4 = (tid & 31) * 4;
    float4 x0 = *(const float4*)&x[(size_t)n*8];
    float4 x1 = *(const float4*)&x[(size_t)n*8+4];
    float xr[8] = {x0.x,x0.y,x0.z,x0.w, x1.x,x1.y,x1.z,x1.w};
    float4 acc = *(const float4*)&b[c4];
    #pragma unroll
    for (int k=0;k<8;k++){
      float4 wv = *(const float4*)&w[k*128 + c4];
      acc.x += xr[k]*wv.x; acc.y += xr[k]*wv.y; acc.z += xr[k]*wv.z; acc.w += xr[k]*wv.w;
    }
    ushort4 o; o.x=f2bf(acc.x); o.y=f2bf(acc.y); o.z=f2bf(acc.z); o.w=f2bf(acc.w);
    *(ushort4*)&hb[(size_t)n*128 + c4] = o;
  }
  float s0=0.f,s1=0.f,s2=0.f;
  int nt4 = (E+3)>>2;
  for (int t4 = tid0; t4 < nt4; t4 += stride){
    int e0 = t4*4;
    if (e0+3 < E){
      float4 a0 = *(const float4*)&ea[(size_t)e0*3];
      float4 a1 = *(const float4*)&ea[(size_t)e0*3+4];
      float4 a2 = *(const float4*)&ea[(size_t)e0*3+8];
      int4 d4 = *(const int4*)&dst[e0];
      s0 += a0.x + a0.w + a1.z + a2.y;
      s1 += a0.y + a1.x + a1.w + a2.z;
      s2 += a0.z + a1.y + a2.x + a2.w;
      int4 r;
      r.x = atomicAdd(&cnt[d4.x], 1);
      r.y = atomicAdd(&cnt[d4.y], 1);
      r.z = atomicAdd(&cnt[d4.z], 1);
      r.w = atomicAdd(&cnt[d4.w], 1);
      *(int4*)&rank[e0] = r;
    } else {
      for(int e=e0; e<E; ++e){
        s0 += ea[(size_t)e*3]; s1 += ea[(size_t)e*3+1]; s2 += ea[(size_t)e*3+2];
        rank[e] = atomicAdd(&cnt[dst[e]], 1);
      }
    }
  }
  #pragma unroll
  for (int m=32;m;m>>=1){ s0 += __shfl_xor(s0,m); s1 += __shfl_xor(s1,m); s2 += __shfl_xor(s2,m); }
  __shared__ float ls[3][8];
  int wv = threadIdx.x>>6;
  if ((threadIdx.x&63)==0){ ls[0][wv]=s0; ls[1][wv]=s1; ls[2][wv]=s2; }
  __syncthreads();
  if (threadIdx.x==0){
    float a=0.f,bb=0.f,c=0.f;
    int nw = blockDim.x>>6;
    for(int i=0;i<nw;i++){ a+=ls[0][i]; bb+=ls[1][i]; c+=ls[2][i]; }
    atomicAdd(&emean[0],a); atomicAdd(&emean[1],bb); atomicAdd(&emean[2],c);
  }
}

// ---------------- CSR scan ----------------
__global__ void scan1_k(const int* __restrict__ cnt, int* __restrict__ incl, int* __restrict__ bsum, int n){
  __shared__ int s[1024];
  int i = blockIdx.x*1024 + threadIdx.x;
  int v = (i<n)? cnt[i] : 0;
  s[threadIdx.x]=v; __syncthreads();
  for(int off=1;off<1024;off<<=1){
    int t = (threadIdx.x>=off)? s[threadIdx.x-off] : 0;
    __syncthreads();
    s[threadIdx.x]+=t; __syncthreads();
  }
  if(i<n) incl[i]=s[threadIdx.x];
  if(threadIdx.x==1023) bsum[blockIdx.x]=s[1023];
}
__global__ void scan2_k(const int* __restrict__ bsum, int* __restrict__ boff, int nb){
  __shared__ int s[256];
  int t = threadIdx.x;
  int v = (t<nb)? bsum[t] : 0;
  s[t]=v; __syncthreads();
  for(int off=1;off<256;off<<=1){
    int tmp = (t>=off)? s[t-off] : 0;
    __syncthreads();
    s[t]+=tmp; __syncthreads();
  }
  if(t<nb) boff[t] = s[t]-v;
}
__global__ void scan3_k(const int* __restrict__ incl, const int* __restrict__ boff, int* __restrict__ row_ptr, int n){
  int i = blockIdx.x*blockDim.x + threadIdx.x;
  if(i<n) row_ptr[i+1] = incl[i] + boff[i>>10];
  if(i==0) row_ptr[0]=0;
}

// one 16B record per edge; NO atomics: pos = row_ptr[dst] + rank
__global__ void csr_fill_k(const int* __restrict__ src, const int* __restrict__ dst,
                           const float* __restrict__ eattr,
                           const int* __restrict__ row_ptr, const int* __restrict__ rank,
                           float4* __restrict__ csr_rec, int E){
  int t = blockIdx.x*blockDim.x + threadIdx.x;
  int e0 = t*4;
  if (e0+3 < E){
    float4 a0 = *(const float4*)&eattr[(size_t)e0*3];
    float4 a1 = *(const float4*)&eattr[(size_t)e0*3+4];
    float4 a2 = *(const float4*)&eattr[(size_t)e0*3+8];
    int4 d4 = *(const int4*)&dst[e0];
    int4 s4 = *(const int4*)&src[e0];
    int4 r4 = *(const int4*)&rank[e0];
    int p0 = row_ptr[d4.x] + r4.x;
    int p1 = row_ptr[d4.y] + r4.y;
    int p2 = row_ptr[d4.z] + r4.z;
    int p3 = row_ptr[d4.w] + r4.w;
    csr_rec[p0] = make_float4(a0.x,a0.y,a0.z, __int_as_float(s4.x));
    csr_rec[p1] = make_float4(a0.w,a1.x,a1.y, __int_as_float(s4.y));
    csr_rec[p2] = make_float4(a1.z,a1.w,a2.x, __int_as_float(s4.z));
    csr_rec[p3] = make_float4(a2.y,a2.z,a2.w, __int_as_float(s4.w));
  } else {
    for(int e=e0; e<E; ++e){
      int d = dst[e];
      int pos = row_ptr[d] + rank[e];
      csr_rec[pos] = make_float4(eattr[(size_t)e*3], eattr[(size_t)e*3+1], eattr[(size_t)e*3+2],
                                 __int_as_float(src[e]));
    }
  }
}

// ---------------- per-layer folded edge-attention params ----------------
__global__ void precompute_k(const float* __restrict__ lin_e, const float* __restrict__ a_e,
                             const float* __restrict__ edge_w, const float* __restrict__ edge_b,
                             const float* __restrict__ emean_sum, float invE,
                             float* __restrict__ params){
  int l = blockIdx.x; int t = threadIdx.x; // 128 threads
  __shared__ float Ve[128][4];
  __shared__ float sW3[12]; __shared__ float sce[4];
  const float* Le = lin_e + (size_t)l*16384; const float* Ae = a_e + l*128;
  #pragma unroll
  for(int h=0; h<4; h++){
    float v=0.f;
    for(int c=0;c<32;c++) v += Le[t*128 + h*32 + c]*Ae[h*32+c];
    Ve[t][h]=v;
  }
  __syncthreads();
  float* P = params + l*32;
  if(t<12){ int k=t>>2, h=t&3; float v=0.f; for(int d=0;d<128;d++) v += edge_w[k*128+d]*Ve[d][h]; P[t]=v; sW3[t]=v; }
  if(t>=16 && t<20){ int h=t-16; float v=0.f; for(int d=0;d<128;d++) v += edge_b[d]*Ve[d][h]; P[12+h]=v; sce[h]=v; }
  __syncthreads();
  if(t<4){
    float v = sce[t];
    for(int k=0;k<3;k++) v += emean_sum[k]*invE * sW3[k*4+t];
    P[16+t]=v;
  }
}

// ---------------- pre-pack gat_lin into bf16 MFMA B-fragments ----------------
__global__ void prepack_w_k(const float* __restrict__ gat_lin, short8v* __restrict__ wpack){
  int l = blockIdx.x; int t = threadIdx.x; // 256 threads per layer
  const float* W = gat_lin + (size_t)l*16384;
  for(int f = t; f < 2048; f += 256){
    int j = f >> 8, ks = (f >> 6) & 3, lane = f & 63;
    int lo = lane & 15, hi = (lane >> 4) & 3;
    short8v b;
    #pragma unroll
    for(int e=0;e<8;e++) b[e] = (short)f2bf(W[(size_t)(ks*32 + hi*8 + e)*128 + j*16 + lo]);
    wpack[(size_t)l*2048 + f] = b;
  }
}

// ---------------- h_lin = h @ lin via bf16 MFMA, fused a_src/a_dst ----------------
// Output staged through wave-private LDS slice for fully-coalesced 16B stores
// (direct per-element bf16 stores were 4x transaction-inflated).
__global__ __launch_bounds__(256) void mfma_dense_k(const unsigned short* __restrict__ hin,
    const short8v* __restrict__ wpack, const float* __restrict__ att_s, const float* __restrict__ att_d,
    unsigned short* __restrict__ hbf, float* __restrict__ a_src, float* __restrict__ a_dst,
    int N, int ntiles){
  __shared__ unsigned short tile[4][16*128];   // 4 waves x 4KB
  int lane = threadIdx.x & 63;
  int wid  = threadIdx.x >> 6;
  int lo = lane & 15, hi = lane >> 4;
  short8v Bf[8][4];            // [col-tile j][k-step]
  #pragma unroll
  for(int j=0;j<8;j++){
    #pragma unroll
    for(int ks=0;ks<4;ks++)
      Bf[j][ks] = wpack[(j<<8) + (ks<<6) + lane];
  }
  float as[8], ad[8];
  #pragma unroll
  for(int j=0;j<8;j++){ as[j]=att_s[j*16+lo]; ad[j]=att_d[j*16+lo]; }

  for(int t = blockIdx.x*4 + wid; t < ntiles; t += gridDim.x*4){
    int n0 = t*16;
    int arow = n0 + lo; if(arow >= N) arow = N-1;
    short8v A[4];
    #pragma unroll
    for(int ks=0;ks<4;ks++)
      A[ks] = *(const short8v*)&hin[(size_t)arow*128 + ks*32 + hi*8];
    float ps[4][4], pd[4][4];
    #pragma unroll
    for(int r=0;r<4;r++){
      #pragma unroll
      for(int h=0;h<4;h++){ ps[r][h]=0.f; pd[r][h]=0.f; }
    }
    #pragma unroll
    for(int j=0;j<8;j++){
      f32x4 acc = {0.f,0.f,0.f,0.f};
      #pragma unroll
      for(int ks=0;ks<4;ks++)
        acc = __builtin_amdgcn_mfma_f32_16x16x32_bf16(A[ks], Bf[j][ks], acc, 0, 0, 0);
      int h = j>>1;
      #pragma unroll
      for(int r=0;r<4;r++){
        tile[wid][(hi*4+r)*128 + j*16 + lo] = f2bf(acc[r]);
        ps[r][h] += acc[r]*as[j];
        pd[r][h] += acc[r]*ad[j];
      }
    }
    // coalesced store: lane covers 64B of one row; 4 lanes per 256B row
    {
      int row = lane >> 2, seg = lane & 3;
      int grow = n0 + row;
      if(grow < N){
        const unsigned short* lp = &tile[wid][row*128 + seg*32];
        short8v v0 = *(const short8v*)&lp[0];
        short8v v1 = *(const short8v*)&lp[8];
        short8v v2 = *(const short8v*)&lp[16];
        short8v v3 = *(const short8v*)&lp[24];
        short8v* gp = (short8v*)&hbf[(size_t)grow*128 + seg*32];
        gp[0]=v0; gp[1]=v1; gp[2]=v2; gp[3]=v3;
      }
    }
    #pragma unroll
    for(int r=0;r<4;r++){
      #pragma unroll
      for(int h=0;h<4;h++){
        #pragma unroll
        for(int msk=1; msk<16; msk<<=1){
          ps[r][h] += __shfl_xor(ps[r][h], msk);
          pd[r][h] += __shfl_xor(pd[r][h], msk);
        }
      }
    }
    if(lo==0){
      #pragma unroll
      for(int r=0;r<4;r++){
        int row = n0 + hi*4 + r;
        if(row<N){
          *(float4*)&a_src[(size_t)row*4] = make_float4(ps[r][0],ps[r][1],ps[r][2],ps[r][3]);
          *(float4*)&a_dst[(size_t)row*4] = make_float4(pd[r][0],pd[r][1],pd[r][2],pd[r][3]);
        }
      }
    }
  }
}

// ---------------- gather(bf16) + chunked lane-parallel online softmax + bias + LN + ReLU ----------------
// EXACT R6 body (the 107.7us variant).
__global__ void aggregate_k(const unsigned int* __restrict__ hbf, const float* __restrict__ a_src,
    const float* __restrict__ a_dst, const int* __restrict__ row_ptr,
    const float4* __restrict__ csr_rec, const float* __restrict__ params,
    const float* __restrict__ bias, const float* __restrict__ lng, const float* __restrict__ lnb,
    unsigned int* __restrict__ h_out, int N){
  int lane = threadIdx.x & 63;
  int n = blockIdx.x*(blockDim.x>>6) + (threadIdx.x>>6);
  if(n>=N) return;
  int g  = lane >> 4;
  int eh = lane & 3;
  int ee = lane >> 2;
  float W0 = params[eh], W1 = params[4+eh], W2 = params[8+eh];
  float ce = params[12+eh], aes = params[16+eh];
  float adst = a_dst[n*4+eh];
  float m = leakyf(a_src[n*4+eh] + adst + aes);
  float dpart = (ee==0) ? 1.f : 0.f;
  float2 acc;
  {
    unsigned int u = hbf[(size_t)n*64 + lane];
    acc.x = __uint_as_float(u << 16);
    acc.y = __uint_as_float(u & 0xffff0000u);
  }
  int s = row_ptr[n], e = row_ptr[n+1];
  for(int base=s; base<e; base+=16){
    int nv = e - base; if(nv>16) nv=16;
    int sr = 0; float al = -1e30f;
    if(ee < nv){
      float4 rc = csr_rec[base+ee];
      sr = __float_as_int(rc.w);
      al = leakyf(a_src[sr*4+eh] + adst + rc.x*W0 + rc.y*W1 + rc.z*W2 + ce);
    }
    float cm = al;
    cm = fmaxf(cm, __shfl_xor(cm,4));
    cm = fmaxf(cm, __shfl_xor(cm,8));
    cm = fmaxf(cm, __shfl_xor(cm,16));
    cm = fmaxf(cm, __shfl_xor(cm,32));
    float nm = fmaxf(m, cm);
    float sc = __expf(m - nm);
    float p  = __expf(al - nm);
    dpart = dpart*sc + p;
    m = nm;
    unsigned int u[16];
    #pragma unroll
    for(int q=0;q<16;q++){
      int srq = __shfl(sr, q*4);
      u[q] = hbf[(size_t)srq*64 + lane];
    }
    float scg = __shfl(sc, g);
    acc.x *= scg; acc.y *= scg;
    #pragma unroll
    for(int q=0;q<16;q++){
      float pq = __shfl(p, q*4 + g);
      float hx = __uint_as_float(u[q] << 16);
      float hy = __uint_as_float(u[q] & 0xffff0000u);
      acc.x += pq*hx; acc.y += pq*hy;
    }
  }
  float dsum = dpart;
  dsum += __shfl_xor(dsum,4);
  dsum += __shfl_xor(dsum,8);
  dsum += __shfl_xor(dsum,16);
  dsum += __shfl_xor(dsum,32);
  float inv = 1.f/(__shfl(dsum, g) + 1e-16f);
  int c = lane*2;
  float ox = acc.x*inv + bias[c], oy = acc.y*inv + bias[c+1];
  float sum = ox+oy;
  #pragma unroll
  for(int msk=32;msk;msk>>=1) sum += __shfl_xor(sum,msk);
  float mean = sum*(1.f/128.f);
  float dx = ox-mean, dy = oy-mean;
  float sq = dx*dx + dy*dy;
  #pragma unroll
  for(int msk=32;msk;msk>>=1) sq += __shfl_xor(sq,msk);
  float r = rsqrtf(sq*(1.f/128.f) + LN_EPSV);
  float yx = fmaxf(dx*r*lng[c]  + lnb[c],   0.f);
  float yy = fmaxf(dy*r*lng[c+1]+ lnb[c+1], 0.f);
  h_out[(size_t)n*64 + lane] = (unsigned int)f2bf(yx) | ((unsigned int)f2bf(yy) << 16);
}

// ---------------- mean pool over sorted batch (bf16 input) ----------------
__global__ void pool_k(const unsigned short* __restrict__ h, const int* __restrict__ batch,
                       float* __restrict__ sums, float* __restrict__ cntf, int N){
  int t = threadIdx.x; // 128 threads = channels
  int n0 = blockIdx.x*256;
  int nend = n0+256; if (nend > N) nend = N;
  float acc = 0.f; float runc = 0.f; int curb = -1;
  for(int n=n0;n<nend;n++){
    int b = batch[n];
    if(b!=curb){
      if(curb>=0){ atomicAdd(&sums[curb*128+t], acc); if(t==0) atomicAdd(&cntf[curb], runc); }
      acc=0.f; runc=0.f; curb=b;
    }
    acc += bf2f(h[(size_t)n*128+t]);
    runc += 1.f;
  }
  if(curb>=0){ atomicAdd(&sums[curb*128+t], acc); if(t==0) atomicAdd(&cntf[curb], runc); }
}

// ---------------- MLP heads, one block per graph ----------------
__global__ void heads_k(const float* __restrict__ sums, const float* __restrict__ cntf,
    const float* __restrict__ w1a, const float* __restrict__ b1a,
    const float* __restrict__ w2a, const float* __restrict__ b2a,
    const float* __restrict__ w1b, const float* __restrict__ b1b,
    const float* __restrict__ w2b, const float* __restrict__ b2b,
    float* __restrict__ out){
  int g = blockIdx.x, t = threadIdx.x; // 128 threads
  __shared__ float gv[128]; __shared__ float hid[64];
  float c = fmaxf(cntf[g], 1.f);
  gv[t] = sums[g*128+t] / c;
  __syncthreads();
  if(t<64){ float v=b1a[t]; for(int d=0;d<128;d++) v += gv[d]*w1a[d*64+t]; hid[t]=fmaxf(v,0.f); }
  __syncthreads();
  if(t<100){ float v=b2a[t]; for(int j=0;j<64;j++) v += hid[j]*w2a[j*100+t]; out[g*100+t]=v; }
  __syncthreads();
  if(t<64){ float v=b1b[t]; for(int d=0;d<128;d++) v += gv[d]*w1b[d*64+t]; hid[t]=fmaxf(v,0.f); }
  __syncthreads();
  if(t<100){ float v=b2b[t]; for(int j=0;j<64;j++) v += hid[j]*w2b[j*100+t]; out[6400 + g*100+t]=v; }
}

extern "C" void kernel_launch(void* const* d_in, const int* in_sizes, int n_in,
                              void* d_out, int out_size, void* d_ws, size_t ws_size,
                              hipStream_t stream){
  const float* x      = (const float*)d_in[0];
  const int*   ei     = (const int*)d_in[1];
  const float* eattr  = (const float*)d_in[2];
  const int*   batch  = (const int*)d_in[3];
  const float* node_w = (const float*)d_in[4];
  const float* node_b = (const float*)d_in[5];
  const float* edge_w = (const float*)d_in[6];
  const float* edge_b = (const float*)d_in[7];
  const float* gat_lin= (const float*)d_in[8];
  const float* att_s  = (const float*)d_in[9];
  const float* att_d  = (const float*)d_in[10];
  const float* lin_e  = (const float*)d_in[11];
  const float* att_e  = (const float*)d_in[12];
  const float* gat_bias=(const float*)d_in[13];
  const float* ln_g   = (const float*)d_in[14];
  const float* ln_b   = (const float*)d_in[15];

  const int N = in_sizes[0]/8;
  const int E = in_sizes[2]/3;
  const int* srcp = ei;
  const int* dstp = ei + E;

  char* wp = (char*)d_ws;
  auto alloc = [&](size_t bytes)->char*{ char* p = wp; wp += (bytes+255)&~(size_t)255; return p; };
  unsigned short* hb_node  = (unsigned short*) alloc((size_t)N*128*2);
  unsigned short* hbf_tab  = (unsigned short*) alloc((size_t)N*128*2);
  float*  a_srcb  = (float*) alloc((size_t)N*4*4);
  float*  a_dstb  = (float*) alloc((size_t)N*4*4);
  int*    row_ptr = (int*)   alloc((size_t)(N+1)*4);
  int*    cnt     = (int*)   alloc((size_t)N*4);
  int*    rank    = (int*)   alloc((size_t)E*4);
  float4* csr_rec = (float4*)alloc((size_t)E*16);
  int*    incl    = (int*)   alloc((size_t)N*4);
  int     nb      = (N+1023)/1024;
  int*    bsum    = (int*)   alloc((size_t)nb*4);
  int*    boff    = (int*)   alloc((size_t)nb*4);
  float*  emean   = (float*) alloc(16);
  float*  params  = (float*) alloc(4*32*4);
  float*  psums   = (float*) alloc(64*128*4);
  float*  pcnt    = (float*) alloc(64*4);
  short8v* wpack  = (short8v*)alloc((size_t)4*2048*16);
  (void)ws_size; (void)n_in; (void)out_size;

  hipMemsetAsync(cnt, 0, (size_t)N*4, stream);
  hipMemsetAsync(emean, 0, 16, stream);
  hipMemsetAsync(psums, 0, 64*128*4, stream);
  hipMemsetAsync(pcnt, 0, 64*4, stream);

  front_k<<<2048, 256, 0, stream>>>(x, node_w, node_b, hb_node, N, eattr, emean, dstp, cnt, rank, E);
  scan1_k<<<nb, 1024, 0, stream>>>(cnt, incl, bsum, N);
  scan2_k<<<1, 256, 0, stream>>>(bsum, boff, nb);
  scan3_k<<<(N+255)/256, 256, 0, stream>>>(incl, boff, row_ptr, N);
  csr_fill_k<<<((E+3)/4+255)/256, 256, 0, stream>>>(srcp, dstp, eattr, row_ptr, rank, csr_rec, E);
  precompute_k<<<4, 128, 0, stream>>>(lin_e, att_e, edge_w, edge_b, emean, 1.0f/(float)E, params);
  prepack_w_k<<<4, 256, 0, stream>>>(gat_lin, wpack);

  int ntiles = (N+15)/16;
  for(int l=0;l<4;l++){
    mfma_dense_k<<<1024, 256, 0, stream>>>(hb_node, wpack + (size_t)l*2048,
        att_s + l*128, att_d + l*128, hbf_tab, a_srcb, a_dstb, N, ntiles);
    aggregate_k<<<(N+3)/4, 256, 0, stream>>>((const unsigned int*)hbf_tab, a_srcb, a_dstb,
        row_ptr, csr_rec,
        params + l*32, gat_bias + l*128, ln_g + l*128, ln_b + l*128,
        (unsigned int*)hb_node, N);
  }

  pool_k<<<(N+255)/256, 128, 0, stream>>>(hb_node, batch, psums, pcnt, N);
  heads_k<<<64, 128, 0, stream>>>(psums, pcnt,
      (const float*)d_in[16], (const float*)d_in[17], (const float*)d_in[18], (const float*)d_in[19],
      (const float*)d_in[20], (const float*)d_in[21], (const float*)d_in[22], (const float*)d_in[23],
      (float*)d_out);
}

// Round 18
// 731.204 us; speedup vs baseline: 1.0430x; 1.0430x over previous
//
#include <hip/hip_runtime.h>

#define LEAKY 0.2f
#define LN_EPSV 1e-5f
#define NGRAPH 64

typedef __attribute__((ext_vector_type(8))) short short8v;
typedef __attribute__((ext_vector_type(4))) float f32x4;

static __device__ __forceinline__ float leakyf(float x){ return x >= 0.f ? x : LEAKY*x; }

// round-to-nearest-even f32 -> bf16 (as ushort)
static __device__ __forceinline__ unsigned short f2bf(float f){
  unsigned int u = __float_as_uint(f);
  u = (u + 0x7fffu + ((u >> 16) & 1u)) >> 16;
  return (unsigned short)u;
}
static __device__ __forceinline__ float bf2f(unsigned short v){
  return __uint_as_float(((unsigned int)v) << 16);
}

// ---------------- fused front: node encoder + edge_attr mean + count&rank ----------------
// The count atomic's RETURN VALUE is the edge's rank within its dst bucket -> stored
// contiguously so csr_fill needs no atomics. node_encode/ea_mean hide under the atomic wall.
__global__ void front_k(const float* __restrict__ x, const float* __restrict__ w,
                        const float* __restrict__ b, unsigned short* __restrict__ hb, int N,
                        const float* __restrict__ ea, float* __restrict__ emean,
                        const int* __restrict__ dst, int* __restrict__ cnt,
                        int* __restrict__ rank, int E){
  int stride = gridDim.x*blockDim.x;
  int tid0 = blockIdx.x*blockDim.x + threadIdx.x;
  // node encode: one item per (n, c4)
  for(int tid = tid0; tid < N*32; tid += stride){
    int n = tid >> 5; int c4 = (tid & 31) * 4;
    float4 x0 = *(const float4*)&x[(size_t)n*8];
    float4 x1 = *(const float4*)&x[(size_t)n*8+4];
    float xr[8] = {x0.x,x0.y,x0.z,x0.w, x1.x,x1.y,x1.z,x1.w};
    float4 acc = *(const float4*)&b[c4];
    #pragma unroll
    for (int k=0;k<8;k++){
      float4 wv = *(const float4*)&w[k*128 + c4];
      acc.x += xr[k]*wv.x; acc.y += xr[k]*wv.y; acc.z += xr[k]*wv.z; acc.w += xr[k]*wv.w;
    }
    ushort4 o; o.x=f2bf(acc.x); o.y=f2bf(acc.y); o.z=f2bf(acc.z); o.w=f2bf(acc.w);
    *(ushort4*)&hb[(size_t)n*128 + c4] = o;
  }
  // ea mean sums + count&rank; 4 edges per item
  float s0=0.f,s1=0.f,s2=0.f;
  int nt4 = (E+3)>>2;
  for (int t4 = tid0; t4 < nt4; t4 += stride){
    int e0 = t4*4;
    if (e0+3 < E){
      float4 a0 = *(const float4*)&ea[(size_t)e0*3];
      float4 a1 = *(const float4*)&ea[(size_t)e0*3+4];
      float4 a2 = *(const float4*)&ea[(size_t)e0*3+8];
      int4 d4 = *(const int4*)&dst[e0];
      s0 += a0.x + a0.w + a1.z + a2.y;
      s1 += a0.y + a1.x + a1.w + a2.z;
      s2 += a0.z + a1.y + a2.x + a2.w;
      int4 r;
      r.x = atomicAdd(&cnt[d4.x], 1);
      r.y = atomicAdd(&cnt[d4.y], 1);
      r.z = atomicAdd(&cnt[d4.z], 1);
      r.w = atomicAdd(&cnt[d4.w], 1);
      *(int4*)&rank[e0] = r;
    } else {
      for(int e=e0; e<E; ++e){
        s0 += ea[(size_t)e*3]; s1 += ea[(size_t)e*3+1]; s2 += ea[(size_t)e*3+2];
        rank[e] = atomicAdd(&cnt[dst[e]], 1);
      }
    }
  }
  #pragma unroll
  for (int m=32;m;m>>=1){ s0 += __shfl_xor(s0,m); s1 += __shfl_xor(s1,m); s2 += __shfl_xor(s2,m); }
  __shared__ float ls[3][8];
  int wv = threadIdx.x>>6;
  if ((threadIdx.x&63)==0){ ls[0][wv]=s0; ls[1][wv]=s1; ls[2][wv]=s2; }
  __syncthreads();
  if (threadIdx.x==0){
    float a=0.f,bb=0.f,c=0.f;
    int nw = blockDim.x>>6;
    for(int i=0;i<nw;i++){ a+=ls[0][i]; bb+=ls[1][i]; c+=ls[2][i]; }
    atomicAdd(&emean[0],a); atomicAdd(&emean[1],bb); atomicAdd(&emean[2],c);
  }
}

// ---------------- CSR scan ----------------
__global__ void scan1_k(const int* __restrict__ cnt, int* __restrict__ incl, int* __restrict__ bsum, int n){
  __shared__ int s[1024];
  int i = blockIdx.x*1024 + threadIdx.x;
  int v = (i<n)? cnt[i] : 0;
  s[threadIdx.x]=v; __syncthreads();
  for(int off=1;off<1024;off<<=1){
    int t = (threadIdx.x>=off)? s[threadIdx.x-off] : 0;
    __syncthreads();
    s[threadIdx.x]+=t; __syncthreads();
  }
  if(i<n) incl[i]=s[threadIdx.x];
  if(threadIdx.x==1023) bsum[blockIdx.x]=s[1023];
}
// parallel exclusive scan over block sums (nb <= 256)
__global__ void scan2_k(const int* __restrict__ bsum, int* __restrict__ boff, int nb){
  __shared__ int s[256];
  int t = threadIdx.x;
  int v = (t<nb)? bsum[t] : 0;
  s[t]=v; __syncthreads();
  for(int off=1;off<256;off<<=1){
    int tmp = (t>=off)? s[t-off] : 0;
    __syncthreads();
    s[t]+=tmp; __syncthreads();
  }
  if(t<nb) boff[t] = s[t]-v;
}
__global__ void scan3_k(const int* __restrict__ incl, const int* __restrict__ boff, int* __restrict__ row_ptr, int n){
  int i = blockIdx.x*blockDim.x + threadIdx.x;
  if(i<n) row_ptr[i+1] = incl[i] + boff[i>>10];
  if(i==0) row_ptr[0]=0;
}

// one 16B record per edge: {attr0, attr1, attr2, src_as_float_bits}; 4 edges per thread
// NO atomics: pos = row_ptr[dst] + rank (rank captured by front_k's counting atomic)
__global__ void csr_fill_k(const int* __restrict__ src, const int* __restrict__ dst,
                           const float* __restrict__ eattr,
                           const int* __restrict__ row_ptr, const int* __restrict__ rank,
                           float4* __restrict__ csr_rec, int E){
  int t = blockIdx.x*blockDim.x + threadIdx.x;
  int e0 = t*4;
  if (e0+3 < E){
    float4 a0 = *(const float4*)&eattr[(size_t)e0*3];
    float4 a1 = *(const float4*)&eattr[(size_t)e0*3+4];
    float4 a2 = *(const float4*)&eattr[(size_t)e0*3+8];
    int4 d4 = *(const int4*)&dst[e0];
    int4 s4 = *(const int4*)&src[e0];
    int4 r4 = *(const int4*)&rank[e0];
    int p0 = row_ptr[d4.x] + r4.x;
    int p1 = row_ptr[d4.y] + r4.y;
    int p2 = row_ptr[d4.z] + r4.z;
    int p3 = row_ptr[d4.w] + r4.w;
    csr_rec[p0] = make_float4(a0.x,a0.y,a0.z, __int_as_float(s4.x));
    csr_rec[p1] = make_float4(a0.w,a1.x,a1.y, __int_as_float(s4.y));
    csr_rec[p2] = make_float4(a1.z,a1.w,a2.x, __int_as_float(s4.z));
    csr_rec[p3] = make_float4(a2.y,a2.z,a2.w, __int_as_float(s4.w));
  } else {
    for(int e=e0; e<E; ++e){
      int d = dst[e];
      int pos = row_ptr[d] + rank[e];
      csr_rec[pos] = make_float4(eattr[(size_t)e*3], eattr[(size_t)e*3+1], eattr[(size_t)e*3+2],
                                 __int_as_float(src[e]));
    }
  }
}

// ---------------- per-layer folded edge-attention params ----------------
__global__ void precompute_k(const float* __restrict__ lin_e, const float* __restrict__ a_e,
                             const float* __restrict__ edge_w, const float* __restrict__ edge_b,
                             const float* __restrict__ emean_sum, float invE,
                             float* __restrict__ params){
  int l = blockIdx.x; int t = threadIdx.x; // 128 threads
  __shared__ float Ve[128][4];
  __shared__ float sW3[12]; __shared__ float sce[4];
  const float* Le = lin_e + (size_t)l*16384; const float* Ae = a_e + l*128;
  #pragma unroll
  for(int h=0; h<4; h++){
    float v=0.f;
    for(int c=0;c<32;c++) v += Le[t*128 + h*32 + c]*Ae[h*32+c];
    Ve[t][h]=v;
  }
  __syncthreads();
  float* P = params + l*32;
  if(t<12){ int k=t>>2, h=t&3; float v=0.f; for(int d=0;d<128;d++) v += edge_w[k*128+d]*Ve[d][h]; P[t]=v; sW3[t]=v; }
  if(t>=16 && t<20){ int h=t-16; float v=0.f; for(int d=0;d<128;d++) v += edge_b[d]*Ve[d][h]; P[12+h]=v; sce[h]=v; }
  __syncthreads();
  if(t<4){
    float v = sce[t];
    for(int k=0;k<3;k++) v += emean_sum[k]*invE * sW3[k*4+t];
    P[16+t]=v;
  }
}

// ---------------- pre-pack gat_lin into bf16 MFMA B-fragments ----------------
__global__ void prepack_w_k(const float* __restrict__ gat_lin, short8v* __restrict__ wpack){
  int l = blockIdx.x; int t = threadIdx.x; // 256 threads per layer
  const float* W = gat_lin + (size_t)l*16384;
  for(int f = t; f < 2048; f += 256){
    int j = f >> 8, ks = (f >> 6) & 3, lane = f & 63;
    int lo = lane & 15, hi = (lane >> 4) & 3;
    short8v b;
    #pragma unroll
    for(int e=0;e<8;e++) b[e] = (short)f2bf(W[(size_t)(ks*32 + hi*8 + e)*128 + j*16 + lo]);
    wpack[(size_t)l*2048 + f] = b;
  }
}

// ---------------- h_lin = h @ lin via bf16 MFMA, fused a_src/a_dst ----------------
__global__ __launch_bounds__(256) void mfma_dense_k(const unsigned short* __restrict__ hin,
    const short8v* __restrict__ wpack, const float* __restrict__ att_s, const float* __restrict__ att_d,
    unsigned short* __restrict__ hbf, float* __restrict__ a_src, float* __restrict__ a_dst,
    int N, int ntiles){
  int lane = threadIdx.x & 63;
  int wid  = threadIdx.x >> 6;
  int lo = lane & 15, hi = lane >> 4;
  short8v Bf[8][4];            // [col-tile j][k-step]
  #pragma unroll
  for(int j=0;j<8;j++){
    #pragma unroll
    for(int ks=0;ks<4;ks++)
      Bf[j][ks] = wpack[(j<<8) + (ks<<6) + lane];
  }
  float as[8], ad[8];
  #pragma unroll
  for(int j=0;j<8;j++){ as[j]=att_s[j*16+lo]; ad[j]=att_d[j*16+lo]; }

  for(int t = blockIdx.x*4 + wid; t < ntiles; t += gridDim.x*4){
    int n0 = t*16;
    int arow = n0 + lo; if(arow >= N) arow = N-1;
    short8v A[4];
    #pragma unroll
    for(int ks=0;ks<4;ks++)
      A[ks] = *(const short8v*)&hin[(size_t)arow*128 + ks*32 + hi*8];
    float ps[4][4], pd[4][4];
    #pragma unroll
    for(int r=0;r<4;r++){
      #pragma unroll
      for(int h=0;h<4;h++){ ps[r][h]=0.f; pd[r][h]=0.f; }
    }
    #pragma unroll
    for(int j=0;j<8;j++){
      f32x4 acc = {0.f,0.f,0.f,0.f};
      #pragma unroll
      for(int ks=0;ks<4;ks++)
        acc = __builtin_amdgcn_mfma_f32_16x16x32_bf16(A[ks], Bf[j][ks], acc, 0, 0, 0);
      int h = j>>1;
      #pragma unroll
      for(int r=0;r<4;r++){
        int row = n0 + hi*4 + r;
        if(row < N) hbf[(size_t)row*128 + j*16 + lo] = f2bf(acc[r]);
        ps[r][h] += acc[r]*as[j];
        pd[r][h] += acc[r]*ad[j];
      }
    }
    #pragma unroll
    for(int r=0;r<4;r++){
      #pragma unroll
      for(int h=0;h<4;h++){
        #pragma unroll
        for(int msk=1; msk<16; msk<<=1){
          ps[r][h] += __shfl_xor(ps[r][h], msk);
          pd[r][h] += __shfl_xor(pd[r][h], msk);
        }
      }
    }
    if(lo==0){
      #pragma unroll
      for(int r=0;r<4;r++){
        int row = n0 + hi*4 + r;
        if(row<N){
          *(float4*)&a_src[(size_t)row*4] = make_float4(ps[r][0],ps[r][1],ps[r][2],ps[r][3]);
          *(float4*)&a_dst[(size_t)row*4] = make_float4(pd[r][0],pd[r][1],pd[r][2],pd[r][3]);
        }
      }
    }
  }
}

// ---------------- gather(bf16) + chunked lane-parallel online softmax + bias + LN + ReLU ----------------
// EXACT R6 body (the 107.7us variant): merged 16B records, 16-slot chunks,
// alpha -> shfl softmax -> branchless straight-line 16-gather issue -> consume.
__global__ void aggregate_k(const unsigned int* __restrict__ hbf, const float* __restrict__ a_src,
    const float* __restrict__ a_dst, const int* __restrict__ row_ptr,
    const float4* __restrict__ csr_rec, const float* __restrict__ params,
    const float* __restrict__ bias, const float* __restrict__ lng, const float* __restrict__ lnb,
    unsigned int* __restrict__ h_out, int N){
  int lane = threadIdx.x & 63;
  int n = blockIdx.x*(blockDim.x>>6) + (threadIdx.x>>6);
  if(n>=N) return;
  int g  = lane >> 4;        // gather head (lane owns channels 2*lane, 2*lane+1)
  int eh = lane & 3;         // alpha head
  int ee = lane >> 2;        // alpha edge slot 0..15
  float W0 = params[eh], W1 = params[4+eh], W2 = params[8+eh];
  float ce = params[12+eh], aes = params[16+eh];
  float adst = a_dst[n*4+eh];
  float m = leakyf(a_src[n*4+eh] + adst + aes);
  float dpart = (ee==0) ? 1.f : 0.f;
  float2 acc;
  {
    unsigned int u = hbf[(size_t)n*64 + lane];   // self message (bf16 pair), scale exp(0)=1
    acc.x = __uint_as_float(u << 16);
    acc.y = __uint_as_float(u & 0xffff0000u);
  }
  int s = row_ptr[n], e = row_ptr[n+1];
  for(int base=s; base<e; base+=16){
    int nv = e - base; if(nv>16) nv=16;
    int sr = 0; float al = -1e30f;
    if(ee < nv){
      float4 rc = csr_rec[base+ee];
      sr = __float_as_int(rc.w);
      al = leakyf(a_src[sr*4+eh] + adst + rc.x*W0 + rc.y*W1 + rc.z*W2 + ce);
    }
    // chunk max across the 16 lanes of this alpha-head (lanes differing in bits 2..5)
    float cm = al;
    cm = fmaxf(cm, __shfl_xor(cm,4));
    cm = fmaxf(cm, __shfl_xor(cm,8));
    cm = fmaxf(cm, __shfl_xor(cm,16));
    cm = fmaxf(cm, __shfl_xor(cm,32));
    float nm = fmaxf(m, cm);
    float sc = __expf(m - nm);          // uniform per alpha-head
    float p  = __expf(al - nm);         // 0 for invalid slots
    dpart = dpart*sc + p;
    m = nm;
    // issue ALL 16 gathers before consuming (invalid slots -> node 0, weight 0)
    unsigned int u[16];
    #pragma unroll
    for(int q=0;q<16;q++){
      int srq = __shfl(sr, q*4);
      u[q] = hbf[(size_t)srq*64 + lane];
    }
    float scg = __shfl(sc, g);
    acc.x *= scg; acc.y *= scg;
    #pragma unroll
    for(int q=0;q<16;q++){
      float pq = __shfl(p, q*4 + g);
      float hx = __uint_as_float(u[q] << 16);
      float hy = __uint_as_float(u[q] & 0xffff0000u);
      acc.x += pq*hx; acc.y += pq*hy;
    }
  }
  float dsum = dpart;
  dsum += __shfl_xor(dsum,4);
  dsum += __shfl_xor(dsum,8);
  dsum += __shfl_xor(dsum,16);
  dsum += __shfl_xor(dsum,32);
  float inv = 1.f/(__shfl(dsum, g) + 1e-16f);
  int c = lane*2;
  float ox = acc.x*inv + bias[c], oy = acc.y*inv + bias[c+1];
  float sum = ox+oy;
  #pragma unroll
  for(int msk=32;msk;msk>>=1) sum += __shfl_xor(sum,msk);
  float mean = sum*(1.f/128.f);
  float dx = ox-mean, dy = oy-mean;
  float sq = dx*dx + dy*dy;
  #pragma unroll
  for(int msk=32;msk;msk>>=1) sq += __shfl_xor(sq,msk);
  float r = rsqrtf(sq*(1.f/128.f) + LN_EPSV);
  float yx = fmaxf(dx*r*lng[c]  + lnb[c],   0.f);
  float yy = fmaxf(dy*r*lng[c+1]+ lnb[c+1], 0.f);
  h_out[(size_t)n*64 + lane] = (unsigned int)f2bf(yx) | ((unsigned int)f2bf(yy) << 16);
}

// ---------------- mean pool over sorted batch (bf16 input) ----------------
__global__ void pool_k(const unsigned short* __restrict__ h, const int* __restrict__ batch,
                       float* __restrict__ sums, float* __restrict__ cntf, int N){
  int t = threadIdx.x; // 128 threads = channels
  int n0 = blockIdx.x*256;
  int nend = n0+256; if (nend > N) nend = N;
  float acc = 0.f; float runc = 0.f; int curb = -1;
  for(int n=n0;n<nend;n++){
    int b = batch[n];
    if(b!=curb){
      if(curb>=0){ atomicAdd(&sums[curb*128+t], acc); if(t==0) atomicAdd(&cntf[curb], runc); }
      acc=0.f; runc=0.f; curb=b;
    }
    acc += bf2f(h[(size_t)n*128+t]);
    runc += 1.f;
  }
  if(curb>=0){ atomicAdd(&sums[curb*128+t], acc); if(t==0) atomicAdd(&cntf[curb], runc); }
}

// ---------------- MLP heads, one block per graph ----------------
__global__ void heads_k(const float* __restrict__ sums, const float* __restrict__ cntf,
    const float* __restrict__ w1a, const float* __restrict__ b1a,
    const float* __restrict__ w2a, const float* __restrict__ b2a,
    const float* __restrict__ w1b, const float* __restrict__ b1b,
    const float* __restrict__ w2b, const float* __restrict__ b2b,
    float* __restrict__ out){
  int g = blockIdx.x, t = threadIdx.x; // 128 threads
  __shared__ float gv[128]; __shared__ float hid[64];
  float c = fmaxf(cntf[g], 1.f);
  gv[t] = sums[g*128+t] / c;
  __syncthreads();
  if(t<64){ float v=b1a[t]; for(int d=0;d<128;d++) v += gv[d]*w1a[d*64+t]; hid[t]=fmaxf(v,0.f); }
  __syncthreads();
  if(t<100){ float v=b2a[t]; for(int j=0;j<64;j++) v += hid[j]*w2a[j*100+t]; out[g*100+t]=v; }
  __syncthreads();
  if(t<64){ float v=b1b[t]; for(int d=0;d<128;d++) v += gv[d]*w1b[d*64+t]; hid[t]=fmaxf(v,0.f); }
  __syncthreads();
  if(t<100){ float v=b2b[t]; for(int j=0;j<64;j++) v += hid[j]*w2b[j*100+t]; out[6400 + g*100+t]=v; }
}

extern "C" void kernel_launch(void* const* d_in, const int* in_sizes, int n_in,
                              void* d_out, int out_size, void* d_ws, size_t ws_size,
                              hipStream_t stream){
  const float* x      = (const float*)d_in[0];
  const int*   ei     = (const int*)d_in[1];
  const float* eattr  = (const float*)d_in[2];
  const int*   batch  = (const int*)d_in[3];
  const float* node_w = (const float*)d_in[4];
  const float* node_b = (const float*)d_in[5];
  const float* edge_w = (const float*)d_in[6];
  const float* edge_b = (const float*)d_in[7];
  const float* gat_lin= (const float*)d_in[8];
  const float* att_s  = (const float*)d_in[9];
  const float* att_d  = (const float*)d_in[10];
  const float* lin_e  = (const float*)d_in[11];
  const float* att_e  = (const float*)d_in[12];
  const float* gat_bias=(const float*)d_in[13];
  const float* ln_g   = (const float*)d_in[14];
  const float* ln_b   = (const float*)d_in[15];

  const int N = in_sizes[0]/8;
  const int E = in_sizes[2]/3;
  const int* srcp = ei;
  const int* dstp = ei + E;

  char* wp = (char*)d_ws;
  auto alloc = [&](size_t bytes)->char*{ char* p = wp; wp += (bytes+255)&~(size_t)255; return p; };
  unsigned short* hb_node  = (unsigned short*) alloc((size_t)N*128*2);  // node features bf16
  unsigned short* hbf_tab  = (unsigned short*) alloc((size_t)N*128*2);  // h_lin gather table bf16
  float*  a_srcb  = (float*) alloc((size_t)N*4*4);
  float*  a_dstb  = (float*) alloc((size_t)N*4*4);
  int*    row_ptr = (int*)   alloc((size_t)(N+1)*4);
  int*    cnt     = (int*)   alloc((size_t)N*4);
  int*    rank    = (int*)   alloc((size_t)E*4);
  float4* csr_rec = (float4*)alloc((size_t)E*16);
  int*    incl    = (int*)   alloc((size_t)N*4);
  int     nb      = (N+1023)/1024;
  int*    bsum    = (int*)   alloc((size_t)nb*4);
  int*    boff    = (int*)   alloc((size_t)nb*4);
  float*  emean   = (float*) alloc(16);
  float*  params  = (float*) alloc(4*32*4);
  float*  psums   = (float*) alloc(64*128*4);
  float*  pcnt    = (float*) alloc(64*4);
  short8v* wpack  = (short8v*)alloc((size_t)4*2048*16);
  (void)ws_size; (void)n_in; (void)out_size;

  hipMemsetAsync(cnt, 0, (size_t)N*4, stream);
  hipMemsetAsync(emean, 0, 16, stream);
  hipMemsetAsync(psums, 0, 64*128*4, stream);
  hipMemsetAsync(pcnt, 0, 64*4, stream);

  front_k<<<2048, 256, 0, stream>>>(x, node_w, node_b, hb_node, N, eattr, emean, dstp, cnt, rank, E);
  scan1_k<<<nb, 1024, 0, stream>>>(cnt, incl, bsum, N);
  scan2_k<<<1, 256, 0, stream>>>(bsum, boff, nb);
  scan3_k<<<(N+255)/256, 256, 0, stream>>>(incl, boff, row_ptr, N);
  csr_fill_k<<<((E+3)/4+255)/256, 256, 0, stream>>>(srcp, dstp, eattr, row_ptr, rank, csr_rec, E);
  precompute_k<<<4, 128, 0, stream>>>(lin_e, att_e, edge_w, edge_b, emean, 1.0f/(float)E, params);
  prepack_w_k<<<4, 256, 0, stream>>>(gat_lin, wpack);

  int ntiles = (N+15)/16;
  for(int l=0;l<4;l++){
    mfma_dense_k<<<1024, 256, 0, stream>>>(hb_node, wpack + (size_t)l*2048,
        att_s + l*128, att_d + l*128, hbf_tab, a_srcb, a_dstb, N, ntiles);
    aggregate_k<<<(N+3)/4, 256, 0, stream>>>((const unsigned int*)hbf_tab, a_srcb, a_dstb,
        row_ptr, csr_rec,
        params + l*32, gat_bias + l*128, ln_g + l*128, ln_b + l*128,
        (unsigned int*)hb_node, N);
  }

  pool_k<<<(N+255)/256, 128, 0, stream>>>(hb_node, batch, psums, pcnt, N);
  heads_k<<<64, 128, 0, stream>>>(psums, pcnt,
      (const float*)d_in[16], (const float*)d_in[17], (const float*)d_in[18], (const float*)d_in[19],
      (const float*)d_in[20], (const float*)d_in[21], (const float*)d_in[22], (const float*)d_in[23],
      (float*)d_out);
}